// Round 5
// baseline (221.605 us; speedup 1.0000x reference)
//
#include <hip/hip_runtime.h>

typedef __attribute__((ext_vector_type(4))) float f32x4;
typedef __attribute__((ext_vector_type(8))) short bf16x8;
typedef unsigned short USHORT;

static __device__ __forceinline__ float bf2f(USHORT u) {
    return __uint_as_float(((unsigned)u) << 16);
}
static __device__ __forceinline__ USHORT f2bf(float f) {
    unsigned u = __float_as_uint(f);
    unsigned r = u + 0x7FFF + ((u >> 16) & 1);   // RTNE
    return (USHORT)(r >> 16);
}

#define GLDS16(gp, lp) __builtin_amdgcn_global_load_lds(                      \
    (const __attribute__((address_space(1))) unsigned int*)(gp),              \
    (__attribute__((address_space(3))) unsigned int*)(lp), 16, 0, 0)

#define FULL_BARRIER() asm volatile("s_waitcnt vmcnt(0) lgkmcnt(0)\ns_barrier" ::: "memory")

#define D64 0.52559648f              // 0.99^64
#define L2D (-0.014499569695115089f) // log2(0.99)

// ---------------------------------------------------------------------------
// Prep: z<5 -> transpose+cast weight z; z==5 -> cast x fp32->bf16.
// ---------------------------------------------------------------------------
struct PrepArgs { const float* src[5]; USHORT* dst[5]; const float* x; USHORT* xb; };

__global__ __launch_bounds__(256) void k_prep(PrepArgs pa) {
    const int z = blockIdx.z;
    const int tid = threadIdx.x;
    __shared__ USHORT t[64][65];
    if (z < 5) {
        const float* __restrict__ W  = pa.src[z];
        USHORT* __restrict__      WT = pa.dst[z];
        const int k0 = blockIdx.y * 64, n0 = blockIdx.x * 64;
#pragma unroll
        for (int s = 0; s < 4; s++) {
            int slot = tid + s * 256;
            int row = slot >> 4, c4 = (slot & 15) * 4;
            float4 vv = *(const float4*)&W[(size_t)(k0 + row) * 1024 + n0 + c4];
            t[row][c4 + 0] = f2bf(vv.x);
            t[row][c4 + 1] = f2bf(vv.y);
            t[row][c4 + 2] = f2bf(vv.z);
            t[row][c4 + 3] = f2bf(vv.w);
        }
        __syncthreads();
#pragma unroll
        for (int s = 0; s < 2; s++) {
            int slot = tid + s * 256;
            int n = slot >> 3, c8 = (slot & 7) * 8;
            USHORT tmp[8];
#pragma unroll
            for (int u = 0; u < 8; u++) tmp[u] = t[c8 + u][n];
            *(int4*)&WT[(size_t)(n0 + n) * 1024 + k0 + c8] = *(int4*)tmp;
        }
    } else {
        const int bi = blockIdx.y * 16 + blockIdx.x;
        const float* xs = pa.x + (size_t)bi * 16384;
        USHORT* xd = pa.xb + (size_t)bi * 16384;
#pragma unroll
        for (int u = 0; u < 16; u++) {
            int idx = u * 1024 + tid * 4;
            float4 v = *(const float4*)&xs[idx];
            *(ushort4*)&xd[idx] = make_ushort4(f2bf(v.x), f2bf(v.y), f2bf(v.z), f2bf(v.w));
        }
    }
}

// ---------------------------------------------------------------------------
// Shared GEMM argument block.
// modes: 0 bf16*scale; 1 sigmoid; 2 VT scatter (+decay); 3 fp32; 4 bf16*scale*0.99^(s&63)
// ---------------------------------------------------------------------------
struct GArgs {
    const USHORT* A;
    const USHORT* W[4];
    const float*  bias[4];
    void*         dst[4];
    USHORT*       dstv;
    float         scale[4];
    int           mode[4];
};

// ---------------------------------------------------------------------------
// Lean GEMM (128^2 2-phase): output projection + safety fallback.
// ---------------------------------------------------------------------------
__global__ __launch_bounds__(256, 2) void k_gemm(GArgs ga) {
    const int z = blockIdx.z;
    const USHORT* __restrict__ A  = ga.A;
    const USHORT* __restrict__ BT = ga.W[z];
    __shared__ USHORT As[2][128 * 32];
    __shared__ USHORT Bs[2][128 * 32];
    const int tid = threadIdx.x;
    const int m0 = blockIdx.y * 128, n0 = blockIdx.x * 128;
    const int w = tid >> 6, l = tid & 63, lr = l & 15, q = l >> 4;
    const int wr = w >> 1, wc = w & 1;
    const int srow = tid >> 2, sco = (tid & 3) * 8;
    const int scol = (((tid & 3) ^ ((tid >> 3) & 3)) << 3);
    const int kread = ((q ^ ((lr >> 1) & 3)) << 3);
    f32x4 acc[4][4] = {};
    GLDS16(&A [(size_t)(m0 + srow)      * 1024 + scol], &As[0][srow * 32 + sco]);
    GLDS16(&A [(size_t)(m0 + srow + 64) * 1024 + scol], &As[0][(srow + 64) * 32 + sco]);
    GLDS16(&BT[(size_t)(n0 + srow)      * 1024 + scol], &Bs[0][srow * 32 + sco]);
    GLDS16(&BT[(size_t)(n0 + srow + 64) * 1024 + scol], &Bs[0][(srow + 64) * 32 + sco]);
    for (int kt = 0; kt < 32; kt++) {
        const int cur = kt & 1;
        FULL_BARRIER();
        if (kt + 1 < 32) {
            const int k1 = (kt + 1) * 32;
            const int nxt = 1 - cur;
            GLDS16(&A [(size_t)(m0 + srow)      * 1024 + k1 + scol], &As[nxt][srow * 32 + sco]);
            GLDS16(&A [(size_t)(m0 + srow + 64) * 1024 + k1 + scol], &As[nxt][(srow + 64) * 32 + sco]);
            GLDS16(&BT[(size_t)(n0 + srow)      * 1024 + k1 + scol], &Bs[nxt][srow * 32 + sco]);
            GLDS16(&BT[(size_t)(n0 + srow + 64) * 1024 + k1 + scol], &Bs[nxt][(srow + 64) * 32 + sco]);
        }
        bf16x8 af[4], bfr[4];
#pragma unroll
        for (int mi = 0; mi < 4; mi++)
            af[mi] = *(const bf16x8*)&As[cur][(wr * 64 + mi * 16 + lr) * 32 + kread];
#pragma unroll
        for (int ni = 0; ni < 4; ni++)
            bfr[ni] = *(const bf16x8*)&Bs[cur][(wc * 64 + ni * 16 + lr) * 32 + kread];
#pragma unroll
        for (int mi = 0; mi < 4; mi++)
#pragma unroll
            for (int ni = 0; ni < 4; ni++)
                acc[mi][ni] = __builtin_amdgcn_mfma_f32_16x16x32_bf16(
                    af[mi], bfr[ni], acc[mi][ni], 0, 0, 0);
    }
    const float scale = ga.scale[z];
    const int mode = ga.mode[z];
    const float* __restrict__ bias = ga.bias[z];
#pragma unroll
    for (int ni = 0; ni < 4; ni++) {
        int col = n0 + wc * 64 + ni * 16 + lr;
        float bv = bias[col];
#pragma unroll
        for (int mi = 0; mi < 4; mi++) {
            int r0 = m0 + wr * 64 + mi * 16 + q * 4;
            float vr[4];
            float d0 = (mode == 4) ? exp2f(L2D * (float)(r0 & 63)) : 1.0f;
#pragma unroll
            for (int r = 0; r < 4; r++) {
                float v = acc[mi][ni][r] + bv;
                if (mode == 1) v = 1.0f / (1.0f + __expf(-v));
                v *= scale;
                if (mode == 4) { v *= d0; d0 *= 0.99f; }
                vr[r] = v;
            }
            if (mode == 3) {
                float* df = (float*)ga.dst[z];
#pragma unroll
                for (int r = 0; r < 4; r++)
                    df[(size_t)(r0 + r) * 1024 + col] = vr[r];
            } else if (mode == 2) {
                int b = r0 >> 11, s = r0 & 2047;
                int h = col >> 6, d = col & 63;
                const float NP1 = 1.0101010101010102f;
                float c0 = exp2f(-L2D * (float)(s & 63));
                float c1 = c0 * NP1, c2 = c1 * NP1, c3 = c2 * NP1;
                *(ushort4*)&ga.dstv[(size_t)(((b * 16 + h) * 64) + d) * 2048 + s] =
                    make_ushort4(f2bf(vr[0] * c0), f2bf(vr[1] * c1),
                                 f2bf(vr[2] * c2), f2bf(vr[3] * c3));
            } else {
                USHORT* db = (USHORT*)ga.dst[z];
#pragma unroll
                for (int r = 0; r < 4; r++)
                    db[(size_t)(r0 + r) * 1024 + col] = f2bf(vr[r]);
            }
        }
    }
}

// ---------------------------------------------------------------------------
// 256^2-tile 8-phase GEMM (T1..T5) for the fused projections.
// K-loop = R3 (ledger-verified, conflict-free).  Epilogue = R3 scatter
// (R4's LDS-transpose epilogue measured −5us regression; reverted).
// ---------------------------------------------------------------------------
#define LDSA(buf, kh) (((buf) * 2 + (kh)) * 8192)
#define LDSB(buf, kh) (32768 + ((buf) * 2 + (kh)) * 8192)
#define BAR() asm volatile("s_barrier" ::: "memory")
#define VM8() asm volatile("s_waitcnt vmcnt(8)" ::: "memory")

#define STAGE_A(ks, kh, buf) do {                                             \
    const USHORT* s_ = aBase + (ks) * 64 + (kh) * 32;                         \
    GLDS16(s_,          &lds[LDSA(buf, kh) + ldsT]);                          \
    GLDS16(s_ + 131072, &lds[LDSA(buf, kh) + 4096 + ldsT]); } while (0)

#define STAGE_B(ks, kh, buf) do {                                             \
    const USHORT* s_ = bBase + (ks) * 64 + (kh) * 32;                         \
    GLDS16(s_,          &lds[LDSB(buf, kh) + ldsT]);                          \
    GLDS16(s_ + 131072, &lds[LDSB(buf, kh) + 4096 + ldsT]); } while (0)

#define PHASE256(buf, kh, mg, LOADB, STAGE_STMT, WAITSTMT) do {               \
    _Pragma("unroll")                                                         \
    for (int mi = 0; mi < 4; mi++)                                            \
        af[mi] = *(const bf16x8*)&lds[LDSA(buf, kh) + aoff + ((mg) * 4 + mi) * 512]; \
    if (LOADB) {                                                              \
        _Pragma("unroll")                                                     \
        for (int ni = 0; ni < 4; ni++)                                        \
            bfrag[ni] = *(const bf16x8*)&lds[LDSB(buf, kh) + boff + ni * 512];\
    }                                                                         \
    STAGE_STMT;                                                               \
    BAR();                                                                    \
    __builtin_amdgcn_s_setprio(1);                                            \
    _Pragma("unroll")                                                         \
    for (int mi = 0; mi < 4; mi++)                                            \
        _Pragma("unroll")                                                     \
        for (int ni = 0; ni < 4; ni++)                                        \
            acc[(mg) * 4 + mi][ni] = __builtin_amdgcn_mfma_f32_16x16x32_bf16( \
                af[mi], bfrag[ni], acc[(mg) * 4 + mi][ni], 0, 0, 0);          \
    __builtin_amdgcn_s_setprio(0);                                            \
    WAITSTMT;                                                                 \
    BAR();                                                                    \
} while (0)

__global__ __launch_bounds__(512, 2) void k_gemm256(GArgs ga) {
    extern __shared__ USHORT lds[];
    int bid = blockIdx.x + 4 * (blockIdx.y + 16 * blockIdx.z);
    bid = (bid & 7) * 32 + (bid >> 3);
    const int bz = bid >> 6;
    const int by = (bid >> 2) & 15;
    const int bx = bid & 3;
    const int z = bz;
    const USHORT* __restrict__ A  = ga.A;
    const USHORT* __restrict__ BT = ga.W[z];
    const int m0 = by * 256, n0 = bx * 256;
    const int tid = threadIdx.x;
    const int wid = tid >> 6, l = tid & 63, lr = l & 15, q = l >> 4;
    const int wr = wid >> 2, wc = wid & 3;
    const int srow = tid >> 2;
    const int scol = (((tid & 3) ^ ((tid >> 3) & 3)) << 3);
    const USHORT* aBase = A  + (size_t)(m0 + srow) * 1024 + scol;
    const USHORT* bBase = BT + (size_t)(n0 + srow) * 1024 + scol;
    const int ldsT = tid * 8;
    const int kread = ((q ^ ((lr >> 1) & 3)) << 3);
    const int aoff = (wr * 128 + lr) * 32 + kread;
    const int boff = (wc * 64 + lr) * 32 + kread;
    f32x4 acc[8][4] = {};
    bf16x8 af[4], bfrag[4];

    STAGE_A(0, 0, 0); STAGE_B(0, 0, 0);
    STAGE_A(0, 1, 0); STAGE_B(0, 1, 0);
    STAGE_A(1, 0, 1); STAGE_B(1, 0, 1);
    VM8();
    BAR();

    for (int kt = 0; kt < 16; kt += 2) {
        const int ks1 = kt + 1;
        const int ks2 = (kt + 2 < 16) ? kt + 2 : 15;
        const int ks3 = (kt + 2 < 16) ? kt + 2 : 15;
        const int ks4 = (kt + 3 < 16) ? kt + 3 : 15;
        PHASE256(0, 0, 0, 1, STAGE_A(ks1, 1, 1), (void)0);
        PHASE256(0, 0, 1, 0, STAGE_B(ks1, 1, 1), VM8());
        PHASE256(0, 1, 0, 1, STAGE_A(ks2, 0, 0), (void)0);
        PHASE256(0, 1, 1, 0, STAGE_B(ks2, 0, 0), VM8());
        PHASE256(1, 0, 0, 1, STAGE_A(ks3, 1, 0), (void)0);
        PHASE256(1, 0, 1, 0, STAGE_B(ks3, 1, 0), VM8());
        PHASE256(1, 1, 0, 1, STAGE_A(ks4, 0, 1), (void)0);
        PHASE256(1, 1, 1, 0, STAGE_B(ks4, 0, 1), VM8());
    }

    const float scale = ga.scale[z];
    const int mode = ga.mode[z];
    const float* __restrict__ bias = ga.bias[z];
#pragma unroll
    for (int ni = 0; ni < 4; ni++) {
        int col = n0 + wc * 64 + ni * 16 + lr;
        float bv = bias[col];
#pragma unroll
        for (int mi = 0; mi < 8; mi++) {
            int r0 = m0 + wr * 128 + mi * 16 + q * 4;
            float vr[4];
            float d0 = (mode == 4) ? exp2f(L2D * (float)(r0 & 63)) : 1.0f;
#pragma unroll
            for (int r = 0; r < 4; r++) {
                float v = acc[mi][ni][r] + bv;
                if (mode == 1) v = 1.0f / (1.0f + __expf(-v));
                v *= scale;
                if (mode == 4) { v *= d0; d0 *= 0.99f; }
                vr[r] = v;
            }
            if (mode == 3) {
                float* df = (float*)ga.dst[z];
#pragma unroll
                for (int r = 0; r < 4; r++)
                    df[(size_t)(r0 + r) * 1024 + col] = vr[r];
            } else if (mode == 2) {
                int b = r0 >> 11, s = r0 & 2047;
                int h = col >> 6, d = col & 63;
                const float NP1 = 1.0101010101010102f;
                float c0 = exp2f(-L2D * (float)(s & 63));
                float c1 = c0 * NP1, c2 = c1 * NP1, c3 = c2 * NP1;
                *(ushort4*)&ga.dstv[(size_t)(((b * 16 + h) * 64) + d) * 2048 + s] =
                    make_ushort4(f2bf(vr[0] * c0), f2bf(vr[1] * c1),
                                 f2bf(vr[2] * c2), f2bf(vr[3] * c3));
            } else {
                USHORT* db = (USHORT*)ga.dst[z];
#pragma unroll
                for (int r = 0; r < 4; r++)
                    db[(size_t)(r0 + r) * 1024 + col] = f2bf(vr[r]);
            }
        }
    }
}

// ---------------------------------------------------------------------------
// U_c = 0.99^64 * V'_c^T @ K_c  fp32 at slot (bh,c) in U (=d_out).
// KT scatter-writes XOR-swizzled (was 8-way bank conflict -> conflict-free);
// Vs staged via global_load_lds with source-side XOR (conflict-free reads).
// ---------------------------------------------------------------------------
__global__ __launch_bounds__(256) void k_attn_u(const USHORT* __restrict__ K,
                                                const USHORT* __restrict__ VT,
                                                float* __restrict__ U) {
    const int bh = blockIdx.x, c = blockIdx.y;
    const int b = bh >> 4, h = bh & 15;
    const int tid = threadIdx.x, w = tid >> 6, l = tid & 63, lr = l & 15, q = l >> 4;
    __shared__ USHORT KT[64 * 72];
    __shared__ USHORT Vs[64 * 64];
#pragma unroll
    for (int s = 0; s < 2; s++) {
        int slot = tid + s * 256;
        // K -> KT transpose: element (d, srow): chunk (srow>>3) stored XOR (d>>3)&7
        int row = slot >> 3, co = (slot & 7) * 8;
        USHORT kv[8];
        *(int4*)kv = *(const int4*)&K[(size_t)(b * 2048 + c * 64 + row) * 1024 + h * 64 + co];
#pragma unroll
        for (int u = 0; u < 8; u++) {
            int d = co + u;
            KT[d * 72 + ((((row >> 3) ^ ((d >> 3) & 7)) << 3) | (row & 7))] = kv[u];
        }
        // Vs glds: LDS chunk C linear; source chunk j ^ (r&7)
        int r_ = slot >> 3, j_ = slot & 7;
        int js_ = ((j_ ^ (r_ & 7)) << 3);
        GLDS16(&VT[(size_t)(bh * 64 + r_) * 2048 + c * 64 + js_], &Vs[slot * 8]);
    }
    FULL_BARRIER();
    f32x4 acc[4] = {};
    bf16x8 av[2];
    {
        const int row = w * 16 + lr;
#pragma unroll
        for (int kk = 0; kk < 2; kk++)
            av[kk] = *(const bf16x8*)&Vs[row * 64 + (((kk * 4 + q) ^ (row & 7)) << 3)];
    }
#pragma unroll
    for (int dkt = 0; dkt < 4; dkt++) {
        const int dp = dkt * 16 + lr;
#pragma unroll
        for (int kk = 0; kk < 2; kk++) {
            bf16x8 bk = *(const bf16x8*)&KT[dp * 72 + (((kk * 4 + q) ^ ((dp >> 3) & 7)) << 3)];
            acc[dkt] = __builtin_amdgcn_mfma_f32_16x16x32_bf16(av[kk], bk, acc[dkt], 0, 0, 0);
        }
    }
    float* slot = U + (size_t)(bh * 32 + c) * 4096;
#pragma unroll
    for (int dkt = 0; dkt < 4; dkt++)
#pragma unroll
        for (int r = 0; r < 4; r++)
            slot[(w * 16 + q * 4 + r) * 64 + dkt * 16 + lr] = acc[dkt][r] * D64;
}

// ---------------------------------------------------------------------------
// Decayed prefix scan, in place, emitting hi/lo-packed u32 (bit-identical to
// apply's old per-block packing): S_c = U_c + D64*S_{c-1}; slot <- pack(S_c).
// ---------------------------------------------------------------------------
__global__ __launch_bounds__(256) void k_scan(float* __restrict__ U) {
    const int bh = blockIdx.x;
    const int idx4 = blockIdx.y * 256 + threadIdx.x;   // float4 slot 0..1023
    float* base = U + (size_t)bh * 32 * 4096 + idx4 * 4;
    float4 s = make_float4(0.f, 0.f, 0.f, 0.f);
    for (int c = 0; c < 32; c++) {
        float* p = base + (size_t)c * 4096;
        float4 v = *(const float4*)p;
        s.x = s.x * D64 + v.x;
        s.y = s.y * D64 + v.y;
        s.z = s.z * D64 + v.z;
        s.w = s.w * D64 + v.w;
        unsigned pk[4];
        const float sv[4] = { s.x, s.y, s.z, s.w };
#pragma unroll
        for (int u = 0; u < 4; u++) {
            USHORT hi = f2bf(sv[u]);
            float  lo = sv[u] - bf2f(hi);
            pk[u] = (unsigned)hi | ((unsigned)f2bf(lo) << 16);
        }
        *(uint4*)p = make_uint4(pk[0], pk[1], pk[2], pk[3]);
    }
}

// ---------------------------------------------------------------------------
// Apply: all-glds staging (Q pre-decayed by proj mode 4; S pre-packed by
// k_scan).  Qs/Ks/Vs linear [64][64] with source-XOR chunk swizzle
// (conflict-free frag reads); Spk staged with 16B-chunk XOR (2-way max).
// ---------------------------------------------------------------------------
__global__ __launch_bounds__(256, 2) void k_apply(const USHORT* __restrict__ Q,
                                                  const USHORT* __restrict__ K,
                                                  const USHORT* __restrict__ VT,
                                                  const unsigned* __restrict__ Sp,
                                                  USHORT* __restrict__ R,
                                                  float* __restrict__ stats) {
    const int bh = blockIdx.x, c = blockIdx.y;
    const int b = bh >> 4, h = bh & 15;
    const int i0 = c * 64;
    const int tid = threadIdx.x, w = tid >> 6, l = tid & 63, lr = l & 15, q = l >> 4;
    __shared__ USHORT Qs[64 * 64];
    __shared__ USHORT Ks[64 * 64];
    __shared__ USHORT Vs[64 * 64];
    __shared__ USHORT Ps[4][16 * 72];
    __shared__ unsigned Spk[4096];
#pragma unroll
    for (int s = 0; s < 2; s++) {
        int C = tid + s * 256;                 // 16B chunk id, [0,512)
        int r_ = C >> 3, j_ = C & 7;
        int js_ = ((j_ ^ (r_ & 7)) << 3);      // swizzled source chunk (shorts)
        GLDS16(&Q [(size_t)(b * 2048 + i0 + r_) * 1024 + h * 64 + js_], &Qs[C * 8]);
        GLDS16(&K [(size_t)(b * 2048 + i0 + r_) * 1024 + h * 64 + js_], &Ks[C * 8]);
        GLDS16(&VT[(size_t)(bh * 64 + r_) * 2048 + i0 + js_],           &Vs[C * 8]);
    }
    if (c > 0) {
        const unsigned* sb = Sp + (size_t)(bh * 32 + (c - 1)) * 4096;
#pragma unroll
        for (int s = 0; s < 4; s++) {
            int C = tid + s * 256;             // 16B chunk id, [0,1024)
            int r_ = C >> 4, j_ = C & 15;
            int js_ = ((j_ ^ ((r_ & 7) << 1)) << 2);   // swizzled source (u32)
            GLDS16(&sb[r_ * 64 + js_], &Spk[C * 4]);
        }
    }
    FULL_BARRIER();
    bf16x8 bqf[2];
    {
        const int row = w * 16 + lr;
#pragma unroll
        for (int kk = 0; kk < 2; kk++)
            bqf[kk] = *(const bf16x8*)&Qs[row * 64 + (((kk * 4 + q) ^ (row & 7)) << 3)];
    }
    f32x4 accr[4] = {};
    if (c > 0) {
#pragma unroll
        for (int dt = 0; dt < 4; dt++) {
            const int row = dt * 16 + lr;
#pragma unroll
            for (int kk = 0; kk < 2; kk++) {
                const unsigned* sp =
                    &Spk[row * 64 + ((((kk << 3) + (q << 1)) ^ ((row & 7) << 1)) << 2)];
                uint4 pa = *(const uint4*)sp;
                uint4 pb = *(const uint4*)(sp + 4);
                unsigned pk[8] = { pa.x, pa.y, pa.z, pa.w, pb.x, pb.y, pb.z, pb.w };
                bf16x8 hi, lo;
#pragma unroll
                for (int u = 0; u < 8; u++) {
                    hi[u] = (short)(pk[u] & 0xffffu);
                    lo[u] = (short)(pk[u] >> 16);
                }
                accr[dt] = __builtin_amdgcn_mfma_f32_16x16x32_bf16(hi, bqf[kk], accr[dt], 0, 0, 0);
                accr[dt] = __builtin_amdgcn_mfma_f32_16x16x32_bf16(lo, bqf[kk], accr[dt], 0, 0, 0);
            }
        }
    }
    {   // diag
        f32x4 accp[4] = {};
#pragma unroll
        for (int kk = 0; kk < 2; kk++)
#pragma unroll
            for (int jt = 0; jt < 4; jt++) {
                const int row = jt * 16 + lr;
                bf16x8 akf = *(const bf16x8*)&Ks[row * 64 + (((kk * 4 + q) ^ (row & 7)) << 3)];
                accp[jt] = __builtin_amdgcn_mfma_f32_16x16x32_bf16(akf, bqf[kk], accp[jt], 0, 0, 0);
            }
        const int ii = w * 16 + lr;
#pragma unroll
        for (int jt = 0; jt < 4; jt++) {
            const int jj = jt * 16 + q * 4;
            float v0 = (jj + 0 <= ii) ? accp[jt][0] : 0.0f;
            float v1 = (jj + 1 <= ii) ? accp[jt][1] : 0.0f;
            float v2 = (jj + 2 <= ii) ? accp[jt][2] : 0.0f;
            float v3 = (jj + 3 <= ii) ? accp[jt][3] : 0.0f;
            unsigned w0 = __builtin_amdgcn_perm(
                __float_as_uint(v1), __float_as_uint(v0), 0x07060302u);
            unsigned w1 = __builtin_amdgcn_perm(
                __float_as_uint(v3), __float_as_uint(v2), 0x07060302u);
            *(uint2*)&Ps[w][lr * 72 + jt * 16 + q * 4] = make_uint2(w0, w1);
        }
        asm volatile("s_waitcnt lgkmcnt(0)" ::: "memory");
#pragma unroll
        for (int kk = 0; kk < 2; kk++) {
            bf16x8 bpf = *(const bf16x8*)&Ps[w][lr * 72 + kk * 32 + q * 8];
#pragma unroll
            for (int dt = 0; dt < 4; dt++) {
                const int row = dt * 16 + lr;
                bf16x8 avf = *(const bf16x8*)&Vs[row * 64 + (((kk * 4 + q) ^ (row & 7)) << 3)];
                accr[dt] = __builtin_amdgcn_mfma_f32_16x16x32_bf16(avf, bpf, accr[dt], 0, 0, 0);
            }
        }
    }
    {   // per-head LN stats
        float s1 = 0.f, s2 = 0.f;
#pragma unroll
        for (int dt = 0; dt < 4; dt++)
#pragma unroll
            for (int r = 0; r < 4; r++) {
                float v = accr[dt][r];
                s1 += v; s2 += v * v;
            }
        s1 += __shfl_down(s1, 32); s2 += __shfl_down(s2, 32);
        s1 += __shfl_down(s1, 16); s2 += __shfl_down(s2, 16);
        if (q == 0) {
            int row = b * 2048 + i0 + w * 16 + lr;
            *(float2*)&stats[((size_t)row * 16 + h) * 2] = make_float2(s1, s2);
        }
    }
    {   // write R bf16 in-place over K's staged region
        const int i = i0 + w * 16 + lr;
#pragma unroll
        for (int dt = 0; dt < 4; dt++) {
            f32x4 a = accr[dt];
            *(ushort4*)&R[(size_t)(b * 2048 + i) * 1024 + h * 64 + dt * 16 + q * 4] =
                make_ushort4(f2bf(a[0]), f2bf(a[1]), f2bf(a[2]), f2bf(a[3]));
        }
    }
}

// ---------------------------------------------------------------------------
// LayerNorm + gate.
// ---------------------------------------------------------------------------
__global__ __launch_bounds__(256) void k_ln_gate(const USHORT* __restrict__ R,
                                                 const USHORT* __restrict__ G,
                                                 const float* __restrict__ stats,
                                                 const float* __restrict__ gamma,
                                                 const float* __restrict__ beta,
                                                 USHORT* __restrict__ NG) {
    const int row = blockIdx.x, tid = threadIdx.x;
    float s1 = 0.f, s2 = 0.f;
    const float* sp = &stats[(size_t)row * 32];
#pragma unroll
    for (int hh = 0; hh < 8; hh++) {
        float4 v = *(const float4*)(sp + hh * 4);
        s1 += v.x + v.z; s2 += v.y + v.w;
    }
    const float mu  = s1 * (1.0f / 1024.0f);
    const float var = s2 * (1.0f / 1024.0f) - mu * mu;
    const float inv = rsqrtf(fmaxf(var, 0.0f) + 1e-5f);
    ushort4 rv = *(const ushort4*)&R[(size_t)row * 1024 + tid * 4];
    ushort4 g4 = *(const ushort4*)&G[(size_t)row * 1024 + tid * 4];
    float4 gm = *(const float4*)&gamma[tid * 4];
    float4 bt = *(const float4*)&beta[tid * 4];
    float  vv[4]  = { bf2f(rv.x), bf2f(rv.y), bf2f(rv.z), bf2f(rv.w) };
    USHORT gg[4]  = { g4.x, g4.y, g4.z, g4.w };
    float  gmm[4] = { gm.x, gm.y, gm.z, gm.w };
    float  btt[4] = { bt.x, bt.y, bt.z, bt.w };
    USHORT o4[4];
#pragma unroll
    for (int u = 0; u < 4; u++) {
        float nv = (vv[u] - mu) * inv * gmm[u] + btt[u];
        o4[u] = f2bf(nv * bf2f(gg[u]));
    }
    *(ushort4*)&NG[(size_t)row * 1024 + tid * 4] = make_ushort4(o4[0], o4[1], o4[2], o4[3]);
}

// ---------------------------------------------------------------------------
extern "C" void kernel_launch(void* const* d_in, const int* in_sizes, int n_in,
                              void* d_out, int out_size, void* d_ws, size_t ws_size,
                              hipStream_t stream) {
    const float* x     = (const float*)d_in[0];
    const float* Wq    = (const float*)d_in[1];
    const float* bq    = (const float*)d_in[2];
    const float* Wk    = (const float*)d_in[3];
    const float* bk    = (const float*)d_in[4];
    const float* Wv    = (const float*)d_in[5];
    const float* bv    = (const float*)d_in[6];
    const float* Wg    = (const float*)d_in[7];
    const float* bg    = (const float*)d_in[8];
    const float* Wo    = (const float*)d_in[9];
    const float* bo    = (const float*)d_in[10];
    const float* gamma = (const float*)d_in[11];
    const float* beta  = (const float*)d_in[12];

    char* ws = (char*)d_ws;
    const size_t MB = 1 << 20;
    USHORT* WqT = (USHORT*)(ws + 0 * MB);
    USHORT* WkT = (USHORT*)(ws + 2 * MB);
    USHORT* WvT = (USHORT*)(ws + 4 * MB);
    USHORT* WgT = (USHORT*)(ws + 6 * MB);
    USHORT* WoT = (USHORT*)(ws + 8 * MB);
    USHORT* Qb  = (USHORT*)(ws + 10 * MB);
    USHORT* Kb  = (USHORT*)(ws + 18 * MB);   // becomes R bf16 after k_apply
    USHORT* VTb = (USHORT*)(ws + 26 * MB);
    USHORT* Gb  = (USHORT*)(ws + 34 * MB);
    float*  Sts = (float*) (ws + 42 * MB);   // [4096][16][2] per-head partials
    USHORT* NGb = Qb;                        // Qb dead after apply
    USHORT* Xb  = (USHORT*)d_out;            // bf16 x; dead after proj
    float*  Ust = (float*)d_out;             // U -> packed S (in place); dead after apply

    {   // 1. prep
        PrepArgs pa;
        pa.src[0] = Wq; pa.src[1] = Wk; pa.src[2] = Wv; pa.src[3] = Wg; pa.src[4] = Wo;
        pa.dst[0] = WqT; pa.dst[1] = WkT; pa.dst[2] = WvT; pa.dst[3] = WgT; pa.dst[4] = WoT;
        pa.x = x; pa.xb = Xb;
        k_prep<<<dim3(16, 16, 6), 256, 0, stream>>>(pa);
    }
    {   // 2. fused projections: Q(.125 * row-decay, mode 4), K, VT(+decay), G(sigmoid)
        static int s_256ok = -1;
        if (s_256ok < 0) {
            hipError_t e = hipFuncSetAttribute(
                reinterpret_cast<const void*>(&k_gemm256),
                hipFuncAttributeMaxDynamicSharedMemorySize, 131072);
            s_256ok = (e == hipSuccess) ? 1 : 0;
        }
        GArgs ga;
        ga.A = Xb;
        ga.W[0] = WqT; ga.W[1] = WkT; ga.W[2] = WvT; ga.W[3] = WgT;
        ga.bias[0] = bq; ga.bias[1] = bk; ga.bias[2] = bv; ga.bias[3] = bg;
        ga.dst[0] = Qb; ga.dst[1] = Kb; ga.dst[2] = nullptr; ga.dst[3] = Gb;
        ga.dstv = VTb;
        ga.scale[0] = 0.125f; ga.scale[1] = 1.0f; ga.scale[2] = 1.0f; ga.scale[3] = 1.0f;
        ga.mode[0] = 4; ga.mode[1] = 0; ga.mode[2] = 2; ga.mode[3] = 1;
        if (s_256ok)
            k_gemm256<<<dim3(4, 16, 4), 512, 131072, stream>>>(ga);
        else
            k_gemm<<<dim3(8, 32, 4), 256, 0, stream>>>(ga);
    }
    // 3. chunk outer products U
    k_attn_u<<<dim3(32, 32), 256, 0, stream>>>(Kb, VTb, Ust);
    // 3b. decayed prefix scan + hi/lo packing (in place over U)
    k_scan<<<dim3(32, 4), 256, 0, stream>>>(Ust);
    // 4. apply: all-glds staging + diag + cross + LN stats; R over Kb
    k_apply<<<dim3(32, 32), 256, 0, stream>>>(Qb, Kb, VTb, (const unsigned*)Ust, Kb, Sts);
    // 5. LayerNorm + gate -> NGb
    k_ln_gate<<<4096, 256, 0, stream>>>(Kb, Gb, Sts, gamma, beta, NGb);
    {   // 6. output projection (mode 3, 128^2) -> d_out fp32
        GArgs go;
        go.A = NGb;
        for (int i = 0; i < 4; i++) {
            go.W[i] = WoT; go.bias[i] = bo; go.dst[i] = d_out;
            go.scale[i] = 1.0f; go.mode[i] = 3;
        }
        go.dstv = nullptr;
        k_gemm<<<dim3(8, 32, 1), 256, 0, stream>>>(go);
    }
}

// Round 6
// 208.449 us; speedup vs baseline: 1.0631x; 1.0631x over previous
//
#include <hip/hip_runtime.h>

typedef __attribute__((ext_vector_type(4))) float f32x4;
typedef __attribute__((ext_vector_type(8))) short bf16x8;
typedef unsigned short USHORT;

static __device__ __forceinline__ float bf2f(USHORT u) {
    return __uint_as_float(((unsigned)u) << 16);
}
static __device__ __forceinline__ USHORT f2bf(float f) {
    unsigned u = __float_as_uint(f);
    unsigned r = u + 0x7FFF + ((u >> 16) & 1);   // RTNE
    return (USHORT)(r >> 16);
}

#define GLDS16(gp, lp) __builtin_amdgcn_global_load_lds(                      \
    (const __attribute__((address_space(1))) unsigned int*)(gp),              \
    (__attribute__((address_space(3))) unsigned int*)(lp), 16, 0, 0)

#define FULL_BARRIER() asm volatile("s_waitcnt vmcnt(0) lgkmcnt(0)\ns_barrier" ::: "memory")

#define D64 0.52559648f              // 0.99^64
#define L2D (-0.014499569695115089f) // log2(0.99)

// ---------------------------------------------------------------------------
// Prep: z<5 -> transpose+cast weight z; z==5 -> cast x fp32->bf16.
// ---------------------------------------------------------------------------
struct PrepArgs { const float* src[5]; USHORT* dst[5]; const float* x; USHORT* xb; };

__global__ __launch_bounds__(256) void k_prep(PrepArgs pa) {
    const int z = blockIdx.z;
    const int tid = threadIdx.x;
    __shared__ USHORT t[64][65];
    if (z < 5) {
        const float* __restrict__ W  = pa.src[z];
        USHORT* __restrict__      WT = pa.dst[z];
        const int k0 = blockIdx.y * 64, n0 = blockIdx.x * 64;
#pragma unroll
        for (int s = 0; s < 4; s++) {
            int slot = tid + s * 256;
            int row = slot >> 4, c4 = (slot & 15) * 4;
            float4 vv = *(const float4*)&W[(size_t)(k0 + row) * 1024 + n0 + c4];
            t[row][c4 + 0] = f2bf(vv.x);
            t[row][c4 + 1] = f2bf(vv.y);
            t[row][c4 + 2] = f2bf(vv.z);
            t[row][c4 + 3] = f2bf(vv.w);
        }
        __syncthreads();
#pragma unroll
        for (int s = 0; s < 2; s++) {
            int slot = tid + s * 256;
            int n = slot >> 3, c8 = (slot & 7) * 8;
            USHORT tmp[8];
#pragma unroll
            for (int u = 0; u < 8; u++) tmp[u] = t[c8 + u][n];
            *(int4*)&WT[(size_t)(n0 + n) * 1024 + k0 + c8] = *(int4*)tmp;
        }
    } else {
        const int bi = blockIdx.y * 16 + blockIdx.x;
        const float* xs = pa.x + (size_t)bi * 16384;
        USHORT* xd = pa.xb + (size_t)bi * 16384;
#pragma unroll
        for (int u = 0; u < 16; u++) {
            int idx = u * 1024 + tid * 4;
            float4 v = *(const float4*)&xs[idx];
            *(ushort4*)&xd[idx] = make_ushort4(f2bf(v.x), f2bf(v.y), f2bf(v.z), f2bf(v.w));
        }
    }
}

// ---------------------------------------------------------------------------
// Shared GEMM argument block.
// modes: 0 bf16*scale; 1 sigmoid bf16; 2 V->VT[b,h,d,s]*0.99^{-(s&63)}; 3 fp32.
// ---------------------------------------------------------------------------
struct GArgs {
    const USHORT* A;
    const USHORT* W[4];
    const float*  bias[4];
    void*         dst[4];
    USHORT*       dstv;
    float         scale[4];
    int           mode[4];
};

// LDS swizzle (all GEMMs): slot j' = j ^ ((row>>1)&3) on 16B k-blocks.
// Per-cycle service group (8 lanes sharing q) hits bank-quads
// 4*(lr&1) + (q ^ ((lr>>1)&3)) = bijection onto 0..7 -> conflict-free.
// Write side: glds linear dest, source pre-swizzled (same involution).

// ---------------------------------------------------------------------------
// Lean GEMM (128^2 2-phase): projection fallback path only.
// ---------------------------------------------------------------------------
__global__ __launch_bounds__(256, 2) void k_gemm(GArgs ga) {
    const int z = blockIdx.z;
    const USHORT* __restrict__ A  = ga.A;
    const USHORT* __restrict__ BT = ga.W[z];
    __shared__ USHORT As[2][128 * 32];
    __shared__ USHORT Bs[2][128 * 32];
    const int tid = threadIdx.x;
    const int m0 = blockIdx.y * 128, n0 = blockIdx.x * 128;
    const int w = tid >> 6, l = tid & 63, lr = l & 15, q = l >> 4;
    const int wr = w >> 1, wc = w & 1;
    const int srow = tid >> 2, sco = (tid & 3) * 8;
    const int scol = (((tid & 3) ^ ((tid >> 3) & 3)) << 3);
    const int kread = ((q ^ ((lr >> 1) & 3)) << 3);
    f32x4 acc[4][4] = {};
    GLDS16(&A [(size_t)(m0 + srow)      * 1024 + scol], &As[0][srow * 32 + sco]);
    GLDS16(&A [(size_t)(m0 + srow + 64) * 1024 + scol], &As[0][(srow + 64) * 32 + sco]);
    GLDS16(&BT[(size_t)(n0 + srow)      * 1024 + scol], &Bs[0][srow * 32 + sco]);
    GLDS16(&BT[(size_t)(n0 + srow + 64) * 1024 + scol], &Bs[0][(srow + 64) * 32 + sco]);
    for (int kt = 0; kt < 32; kt++) {
        const int cur = kt & 1;
        FULL_BARRIER();
        if (kt + 1 < 32) {
            const int k1 = (kt + 1) * 32;
            const int nxt = 1 - cur;
            GLDS16(&A [(size_t)(m0 + srow)      * 1024 + k1 + scol], &As[nxt][srow * 32 + sco]);
            GLDS16(&A [(size_t)(m0 + srow + 64) * 1024 + k1 + scol], &As[nxt][(srow + 64) * 32 + sco]);
            GLDS16(&BT[(size_t)(n0 + srow)      * 1024 + k1 + scol], &Bs[nxt][srow * 32 + sco]);
            GLDS16(&BT[(size_t)(n0 + srow + 64) * 1024 + k1 + scol], &Bs[nxt][(srow + 64) * 32 + sco]);
        }
        bf16x8 af[4], bfr[4];
#pragma unroll
        for (int mi = 0; mi < 4; mi++)
            af[mi] = *(const bf16x8*)&As[cur][(wr * 64 + mi * 16 + lr) * 32 + kread];
#pragma unroll
        for (int ni = 0; ni < 4; ni++)
            bfr[ni] = *(const bf16x8*)&Bs[cur][(wc * 64 + ni * 16 + lr) * 32 + kread];
#pragma unroll
        for (int mi = 0; mi < 4; mi++)
#pragma unroll
            for (int ni = 0; ni < 4; ni++)
                acc[mi][ni] = __builtin_amdgcn_mfma_f32_16x16x32_bf16(
                    af[mi], bfr[ni], acc[mi][ni], 0, 0, 0);
    }
    const float scale = ga.scale[z];
    const int mode = ga.mode[z];
    const float* __restrict__ bias = ga.bias[z];
#pragma unroll
    for (int ni = 0; ni < 4; ni++) {
        int col = n0 + wc * 64 + ni * 16 + lr;
        float bv = bias[col];
#pragma unroll
        for (int mi = 0; mi < 4; mi++) {
            int r0 = m0 + wr * 64 + mi * 16 + q * 4;
            float vr[4];
#pragma unroll
            for (int r = 0; r < 4; r++) {
                float v = acc[mi][ni][r] + bv;
                if (mode == 1) v = 1.0f / (1.0f + __expf(-v));
                vr[r] = v * scale;
            }
            if (mode == 3) {
                float* df = (float*)ga.dst[z];
#pragma unroll
                for (int r = 0; r < 4; r++)
                    df[(size_t)(r0 + r) * 1024 + col] = vr[r];
            } else if (mode == 2) {
                int b = r0 >> 11, s = r0 & 2047;
                int h = col >> 6, d = col & 63;
                const float NP1 = 1.0101010101010102f;
                float c0 = exp2f(-L2D * (float)(s & 63));
                float c1 = c0 * NP1, c2 = c1 * NP1, c3 = c2 * NP1;
                *(ushort4*)&ga.dstv[(size_t)(((b * 16 + h) * 64) + d) * 2048 + s] =
                    make_ushort4(f2bf(vr[0] * c0), f2bf(vr[1] * c1),
                                 f2bf(vr[2] * c2), f2bf(vr[3] * c3));
            } else {
                USHORT* db = (USHORT*)ga.dst[z];
#pragma unroll
                for (int r = 0; r < 4; r++)
                    db[(size_t)(r0 + r) * 1024 + col] = f2bf(vr[r]);
            }
        }
    }
}

// ---------------------------------------------------------------------------
// Output projection GEMM: 64x128 tiles -> grid (8,64) = 512 blocks = 2+/CU
// co-resident (the old 128^2 path gave only 256 blocks = 1/CU, leaving the
// 2-phase barrier-drain stall completely unhidden).  Same BK=32 2-phase
// structure, same swizzle, same K order -> bit-identical results.
// ---------------------------------------------------------------------------
__global__ __launch_bounds__(256, 2) void k_gemm_out(const USHORT* __restrict__ A,
                                                     const USHORT* __restrict__ BT,
                                                     const float* __restrict__ bias,
                                                     float* __restrict__ C) {
    __shared__ USHORT As[2][64 * 32];
    __shared__ USHORT Bs[2][128 * 32];
    const int tid = threadIdx.x;
    const int m0 = blockIdx.y * 64, n0 = blockIdx.x * 128;
    const int w = tid >> 6, l = tid & 63, lr = l & 15, q = l >> 4;
    const int srow = tid >> 2, sco = (tid & 3) * 8;
    const int scol = (((tid & 3) ^ ((tid >> 3) & 3)) << 3);
    const int kread = ((q ^ ((lr >> 1) & 3)) << 3);
    f32x4 acc[4][2] = {};
    GLDS16(&A [(size_t)(m0 + srow)      * 1024 + scol], &As[0][srow * 32 + sco]);
    GLDS16(&BT[(size_t)(n0 + srow)      * 1024 + scol], &Bs[0][srow * 32 + sco]);
    GLDS16(&BT[(size_t)(n0 + srow + 64) * 1024 + scol], &Bs[0][(srow + 64) * 32 + sco]);
    for (int kt = 0; kt < 32; kt++) {
        const int cur = kt & 1;
        FULL_BARRIER();
        if (kt + 1 < 32) {
            const int k1 = (kt + 1) * 32;
            const int nxt = 1 - cur;
            GLDS16(&A [(size_t)(m0 + srow)      * 1024 + k1 + scol], &As[nxt][srow * 32 + sco]);
            GLDS16(&BT[(size_t)(n0 + srow)      * 1024 + k1 + scol], &Bs[nxt][srow * 32 + sco]);
            GLDS16(&BT[(size_t)(n0 + srow + 64) * 1024 + k1 + scol], &Bs[nxt][(srow + 64) * 32 + sco]);
        }
        bf16x8 af[4], bfr[2];
#pragma unroll
        for (int mi = 0; mi < 4; mi++)
            af[mi] = *(const bf16x8*)&As[cur][(mi * 16 + lr) * 32 + kread];
#pragma unroll
        for (int ni = 0; ni < 2; ni++)
            bfr[ni] = *(const bf16x8*)&Bs[cur][(w * 32 + ni * 16 + lr) * 32 + kread];
#pragma unroll
        for (int mi = 0; mi < 4; mi++)
#pragma unroll
            for (int ni = 0; ni < 2; ni++)
                acc[mi][ni] = __builtin_amdgcn_mfma_f32_16x16x32_bf16(
                    af[mi], bfr[ni], acc[mi][ni], 0, 0, 0);
    }
#pragma unroll
    for (int ni = 0; ni < 2; ni++) {
        const int col = n0 + w * 32 + ni * 16 + lr;
        const float bv = bias[col];
#pragma unroll
        for (int mi = 0; mi < 4; mi++) {
            const int r0 = m0 + mi * 16 + q * 4;
#pragma unroll
            for (int r = 0; r < 4; r++)
                C[(size_t)(r0 + r) * 1024 + col] = acc[mi][ni][r] + bv;
        }
    }
}

// ---------------------------------------------------------------------------
// 256^2-tile 8-phase GEMM (T1..T5) for the fused projections (R3-exact).
// ---------------------------------------------------------------------------
#define LDSA(buf, kh) (((buf) * 2 + (kh)) * 8192)
#define LDSB(buf, kh) (32768 + ((buf) * 2 + (kh)) * 8192)
#define BAR() asm volatile("s_barrier" ::: "memory")
#define VM8() asm volatile("s_waitcnt vmcnt(8)" ::: "memory")

#define STAGE_A(ks, kh, buf) do {                                             \
    const USHORT* s_ = aBase + (ks) * 64 + (kh) * 32;                         \
    GLDS16(s_,          &lds[LDSA(buf, kh) + ldsT]);                          \
    GLDS16(s_ + 131072, &lds[LDSA(buf, kh) + 4096 + ldsT]); } while (0)

#define STAGE_B(ks, kh, buf) do {                                             \
    const USHORT* s_ = bBase + (ks) * 64 + (kh) * 32;                         \
    GLDS16(s_,          &lds[LDSB(buf, kh) + ldsT]);                          \
    GLDS16(s_ + 131072, &lds[LDSB(buf, kh) + 4096 + ldsT]); } while (0)

#define PHASE256(buf, kh, mg, LOADB, STAGE_STMT, WAITSTMT) do {               \
    _Pragma("unroll")                                                         \
    for (int mi = 0; mi < 4; mi++)                                            \
        af[mi] = *(const bf16x8*)&lds[LDSA(buf, kh) + aoff + ((mg) * 4 + mi) * 512]; \
    if (LOADB) {                                                              \
        _Pragma("unroll")                                                     \
        for (int ni = 0; ni < 4; ni++)                                        \
            bfrag[ni] = *(const bf16x8*)&lds[LDSB(buf, kh) + boff + ni * 512];\
    }                                                                         \
    STAGE_STMT;                                                               \
    BAR();                                                                    \
    __builtin_amdgcn_s_setprio(1);                                            \
    _Pragma("unroll")                                                         \
    for (int mi = 0; mi < 4; mi++)                                            \
        _Pragma("unroll")                                                     \
        for (int ni = 0; ni < 4; ni++)                                        \
            acc[(mg) * 4 + mi][ni] = __builtin_amdgcn_mfma_f32_16x16x32_bf16( \
                af[mi], bfrag[ni], acc[(mg) * 4 + mi][ni], 0, 0, 0);          \
    __builtin_amdgcn_s_setprio(0);                                            \
    WAITSTMT;                                                                 \
    BAR();                                                                    \
} while (0)

__global__ __launch_bounds__(512, 2) void k_gemm256(GArgs ga) {
    extern __shared__ USHORT lds[];
    int bid = blockIdx.x + 4 * (blockIdx.y + 16 * blockIdx.z);
    bid = (bid & 7) * 32 + (bid >> 3);
    const int bz = bid >> 6;
    const int by = (bid >> 2) & 15;
    const int bx = bid & 3;
    const int z = bz;
    const USHORT* __restrict__ A  = ga.A;
    const USHORT* __restrict__ BT = ga.W[z];
    const int m0 = by * 256, n0 = bx * 256;
    const int tid = threadIdx.x;
    const int wid = tid >> 6, l = tid & 63, lr = l & 15, q = l >> 4;
    const int wr = wid >> 2, wc = wid & 3;
    const int srow = tid >> 2;
    const int scol = (((tid & 3) ^ ((tid >> 3) & 3)) << 3);
    const USHORT* aBase = A  + (size_t)(m0 + srow) * 1024 + scol;
    const USHORT* bBase = BT + (size_t)(n0 + srow) * 1024 + scol;
    const int ldsT = tid * 8;
    const int kread = ((q ^ ((lr >> 1) & 3)) << 3);
    const int aoff = (wr * 128 + lr) * 32 + kread;
    const int boff = (wc * 64 + lr) * 32 + kread;
    f32x4 acc[8][4] = {};
    bf16x8 af[4], bfrag[4];

    STAGE_A(0, 0, 0); STAGE_B(0, 0, 0);
    STAGE_A(0, 1, 0); STAGE_B(0, 1, 0);
    STAGE_A(1, 0, 1); STAGE_B(1, 0, 1);
    VM8();
    BAR();

    for (int kt = 0; kt < 16; kt += 2) {
        const int ks1 = kt + 1;
        const int ks2 = (kt + 2 < 16) ? kt + 2 : 15;
        const int ks3 = (kt + 2 < 16) ? kt + 2 : 15;
        const int ks4 = (kt + 3 < 16) ? kt + 3 : 15;
        PHASE256(0, 0, 0, 1, STAGE_A(ks1, 1, 1), (void)0);
        PHASE256(0, 0, 1, 0, STAGE_B(ks1, 1, 1), VM8());
        PHASE256(0, 1, 0, 1, STAGE_A(ks2, 0, 0), (void)0);
        PHASE256(0, 1, 1, 0, STAGE_B(ks2, 0, 0), VM8());
        PHASE256(1, 0, 0, 1, STAGE_A(ks3, 1, 0), (void)0);
        PHASE256(1, 0, 1, 0, STAGE_B(ks3, 1, 0), VM8());
        PHASE256(1, 1, 0, 1, STAGE_A(ks4, 0, 1), (void)0);
        PHASE256(1, 1, 1, 0, STAGE_B(ks4, 0, 1), VM8());
    }

    const float scale = ga.scale[z];
    const int mode = ga.mode[z];
    const float* __restrict__ bias = ga.bias[z];
#pragma unroll
    for (int ni = 0; ni < 4; ni++) {
        int col = n0 + wc * 64 + ni * 16 + lr;
        float bv = bias[col];
#pragma unroll
        for (int mi = 0; mi < 8; mi++) {
            int r0 = m0 + wr * 128 + mi * 16 + q * 4;
            float vr[4];
#pragma unroll
            for (int r = 0; r < 4; r++) {
                float v = acc[mi][ni][r] + bv;
                if (mode == 1) v = 1.0f / (1.0f + __expf(-v));
                vr[r] = v * scale;
            }
            if (mode == 3) {
                float* df = (float*)ga.dst[z];
#pragma unroll
                for (int r = 0; r < 4; r++)
                    df[(size_t)(r0 + r) * 1024 + col] = vr[r];
            } else if (mode == 2) {
                int b = r0 >> 11, s = r0 & 2047;
                int h = col >> 6, d = col & 63;
                const float NP1 = 1.0101010101010102f;
                float c0 = exp2f(-L2D * (float)(s & 63));
                float c1 = c0 * NP1, c2 = c1 * NP1, c3 = c2 * NP1;
                *(ushort4*)&ga.dstv[(size_t)(((b * 16 + h) * 64) + d) * 2048 + s] =
                    make_ushort4(f2bf(vr[0] * c0), f2bf(vr[1] * c1),
                                 f2bf(vr[2] * c2), f2bf(vr[3] * c3));
            } else {
                USHORT* db = (USHORT*)ga.dst[z];
#pragma unroll
                for (int r = 0; r < 4; r++)
                    db[(size_t)(r0 + r) * 1024 + col] = f2bf(vr[r]);
            }
        }
    }
}

// ---------------------------------------------------------------------------
// U_c = 0.99^64 * V'_c^T @ K_c  fp32 at slot (bh,c) in U (=d_out).  (R3-exact)
// ---------------------------------------------------------------------------
__global__ __launch_bounds__(256) void k_attn_u(const USHORT* __restrict__ K,
                                                const USHORT* __restrict__ VT,
                                                float* __restrict__ U) {
    const int bh = blockIdx.x, c = blockIdx.y;
    const int b = bh >> 4, h = bh & 15;
    const int tid = threadIdx.x, w = tid >> 6, l = tid & 63, lr = l & 15, q = l >> 4;
    __shared__ USHORT KT[64 * 72];
    __shared__ USHORT Vs[64 * 72];
#pragma unroll
    for (int s = 0; s < 2; s++) {
        int slot = tid + s * 256;
        int row = slot >> 3, co = (slot & 7) * 8;
        USHORT kv[8];
        *(int4*)kv = *(const int4*)&K[(size_t)(b * 2048 + c * 64 + row) * 1024 + h * 64 + co];
#pragma unroll
        for (int u = 0; u < 8; u++) KT[(co + u) * 72 + row] = kv[u];
        *(int4*)&Vs[row * 72 + co] =
            *(const int4*)&VT[(size_t)(bh * 64 + row) * 2048 + c * 64 + co];
    }
    __syncthreads();
    f32x4 acc[4] = {};
    bf16x8 av[2];
#pragma unroll
    for (int kk = 0; kk < 2; kk++)
        av[kk] = *(const bf16x8*)&Vs[(w * 16 + lr) * 72 + kk * 32 + q * 8];
#pragma unroll
    for (int dkt = 0; dkt < 4; dkt++)
#pragma unroll
        for (int kk = 0; kk < 2; kk++) {
            bf16x8 bk = *(const bf16x8*)&KT[(dkt * 16 + lr) * 72 + kk * 32 + q * 8];
            acc[dkt] = __builtin_amdgcn_mfma_f32_16x16x32_bf16(av[kk], bk, acc[dkt], 0, 0, 0);
        }
    float* slot = U + (size_t)(bh * 32 + c) * 4096;
#pragma unroll
    for (int dkt = 0; dkt < 4; dkt++)
#pragma unroll
        for (int r = 0; r < 4; r++)
            slot[(w * 16 + q * 4 + r) * 64 + dkt * 16 + lr] = acc[dkt][r] * D64;
}

// ---------------------------------------------------------------------------
// In-place decayed prefix scan over chunks: S_c = U_c + D64 * S_{c-1}. (R3)
// ---------------------------------------------------------------------------
__global__ __launch_bounds__(256) void k_scan(float* __restrict__ U) {
    const int bh = blockIdx.x;
    const int idx4 = blockIdx.y * 256 + threadIdx.x;
    float* base = U + (size_t)bh * 32 * 4096 + idx4 * 4;
    float4 s = make_float4(0.f, 0.f, 0.f, 0.f);
    for (int c = 0; c < 32; c++) {
        float* p = base + (size_t)c * 4096;
        float4 v = *(const float4*)p;
        s.x = s.x * D64 + v.x;
        s.y = s.y * D64 + v.y;
        s.z = s.z * D64 + v.z;
        s.w = s.w * D64 + v.w;
        *(float4*)p = s;
    }
}

// ---------------------------------------------------------------------------
// Apply (R3-exact): read pre-scanned S_{c-1}, diag masked tile, cross via S,
// per-head LN stats, R bf16 in-place over K's staged region.
// ---------------------------------------------------------------------------
__global__ __launch_bounds__(256, 2) void k_apply(const USHORT* __restrict__ Q,
                                                  const USHORT* __restrict__ K,
                                                  const USHORT* __restrict__ VT,
                                                  const float* __restrict__ U,
                                                  USHORT* __restrict__ R,
                                                  float* __restrict__ stats) {
    const int bh = blockIdx.x, c = blockIdx.y;
    const int b = bh >> 4, h = bh & 15;
    const int i0 = c * 64;
    const int tid = threadIdx.x, w = tid >> 6, l = tid & 63, lr = l & 15, q = l >> 4;
    __shared__ USHORT Qs[64 * 72];
    __shared__ USHORT Ks[64 * 72];
    __shared__ USHORT Vs[64 * 72];
    __shared__ USHORT Ps[4][16 * 72];
    __shared__ unsigned Spk[4096];
#pragma unroll
    for (int s = 0; s < 2; s++) {
        int slot = tid + s * 256;
        int row = slot >> 3, c8 = (slot & 7) * 8;
        USHORT q8[8];
        *(int4*)q8 = *(const int4*)&Q[(size_t)(b * 2048 + i0 + row) * 1024 + h * 64 + c8];
        const float fr = exp2f(L2D * (float)row);   // Q'' = Q * 0.99^{local i}
#pragma unroll
        for (int u = 0; u < 8; u++) q8[u] = f2bf(bf2f(q8[u]) * fr);
        *(int4*)&Qs[row * 72 + c8] = *(int4*)q8;
        *(int4*)&Ks[row * 72 + c8] =
            *(const int4*)&K[(size_t)(b * 2048 + i0 + row) * 1024 + h * 64 + c8];
        *(int4*)&Vs[row * 72 + c8] =
            *(const int4*)&VT[(size_t)(bh * 64 + row) * 2048 + i0 + c8];
    }
    if (c > 0) {
        const float* p = U + (size_t)(bh * 32 + (c - 1)) * 4096 + tid * 16;
        float sa[16];
#pragma unroll
        for (int u4 = 0; u4 < 4; u4++) {
            float4 uv = *(const float4*)(p + u4 * 4);
            sa[u4 * 4 + 0] = uv.x; sa[u4 * 4 + 1] = uv.y;
            sa[u4 * 4 + 2] = uv.z; sa[u4 * 4 + 3] = uv.w;
        }
#pragma unroll
        for (int u = 0; u < 16; u++) {
            USHORT hi = f2bf(sa[u]);
            float  lo = sa[u] - bf2f(hi);
            Spk[tid * 16 + u] = (unsigned)hi | ((unsigned)f2bf(lo) << 16);
        }
    }
    __syncthreads();
    bf16x8 bqf[2];
#pragma unroll
    for (int kk = 0; kk < 2; kk++)
        bqf[kk] = *(const bf16x8*)&Qs[(w * 16 + lr) * 72 + kk * 32 + q * 8];
    f32x4 accr[4] = {};
    if (c > 0) {
#pragma unroll
        for (int dt = 0; dt < 4; dt++)
#pragma unroll
            for (int kk = 0; kk < 2; kk++) {
                const unsigned* sp = &Spk[(dt * 16 + lr) * 64 + kk * 32 + q * 8];
                uint4 pa = *(const uint4*)sp;
                uint4 pb = *(const uint4*)(sp + 4);
                unsigned pk[8] = { pa.x, pa.y, pa.z, pa.w, pb.x, pb.y, pb.z, pb.w };
                bf16x8 hi, lo;
#pragma unroll
                for (int u = 0; u < 8; u++) {
                    hi[u] = (short)(pk[u] & 0xffffu);
                    lo[u] = (short)(pk[u] >> 16);
                }
                accr[dt] = __builtin_amdgcn_mfma_f32_16x16x32_bf16(hi, bqf[kk], accr[dt], 0, 0, 0);
                accr[dt] = __builtin_amdgcn_mfma_f32_16x16x32_bf16(lo, bqf[kk], accr[dt], 0, 0, 0);
            }
    }
    {   // diag
        f32x4 accp[4] = {};
#pragma unroll
        for (int kk = 0; kk < 2; kk++)
#pragma unroll
            for (int jt = 0; jt < 4; jt++) {
                bf16x8 akf = *(const bf16x8*)&Ks[(jt * 16 + lr) * 72 + kk * 32 + q * 8];
                accp[jt] = __builtin_amdgcn_mfma_f32_16x16x32_bf16(akf, bqf[kk], accp[jt], 0, 0, 0);
            }
        const int ii = w * 16 + lr;
#pragma unroll
        for (int jt = 0; jt < 4; jt++) {
            const int jj = jt * 16 + q * 4;
            float v0 = (jj + 0 <= ii) ? accp[jt][0] : 0.0f;
            float v1 = (jj + 1 <= ii) ? accp[jt][1] : 0.0f;
            float v2 = (jj + 2 <= ii) ? accp[jt][2] : 0.0f;
            float v3 = (jj + 3 <= ii) ? accp[jt][3] : 0.0f;
            unsigned w0 = __builtin_amdgcn_perm(
                __float_as_uint(v1), __float_as_uint(v0), 0x07060302u);
            unsigned w1 = __builtin_amdgcn_perm(
                __float_as_uint(v3), __float_as_uint(v2), 0x07060302u);
            *(uint2*)&Ps[w][lr * 72 + jt * 16 + q * 4] = make_uint2(w0, w1);
        }
        asm volatile("s_waitcnt lgkmcnt(0)" ::: "memory");
#pragma unroll
        for (int kk = 0; kk < 2; kk++) {
            bf16x8 bpf = *(const bf16x8*)&Ps[w][lr * 72 + kk * 32 + q * 8];
#pragma unroll
            for (int dt = 0; dt < 4; dt++) {
                bf16x8 avf = *(const bf16x8*)&Vs[(dt * 16 + lr) * 72 + kk * 32 + q * 8];
                accr[dt] = __builtin_amdgcn_mfma_f32_16x16x32_bf16(avf, bpf, accr[dt], 0, 0, 0);
            }
        }
    }
    {   // per-head LN stats: unique (row, h) writer
        float s1 = 0.f, s2 = 0.f;
#pragma unroll
        for (int dt = 0; dt < 4; dt++)
#pragma unroll
            for (int r = 0; r < 4; r++) {
                float v = accr[dt][r];
                s1 += v; s2 += v * v;
            }
        s1 += __shfl_down(s1, 32); s2 += __shfl_down(s2, 32);
        s1 += __shfl_down(s1, 16); s2 += __shfl_down(s2, 16);
        if (q == 0) {
            int row = b * 2048 + i0 + w * 16 + lr;
            *(float2*)&stats[((size_t)row * 16 + h) * 2] = make_float2(s1, s2);
        }
    }
    {   // write R bf16 in-place over K's staged region
        const int i = i0 + w * 16 + lr;
#pragma unroll
        for (int dt = 0; dt < 4; dt++) {
            f32x4 a = accr[dt];
            *(ushort4*)&R[(size_t)(b * 2048 + i) * 1024 + h * 64 + dt * 16 + q * 4] =
                make_ushort4(f2bf(a[0]), f2bf(a[1]), f2bf(a[2]), f2bf(a[3]));
        }
    }
}

// ---------------------------------------------------------------------------
// LayerNorm + gate (R3-exact).
// ---------------------------------------------------------------------------
__global__ __launch_bounds__(256) void k_ln_gate(const USHORT* __restrict__ R,
                                                 const USHORT* __restrict__ G,
                                                 const float* __restrict__ stats,
                                                 const float* __restrict__ gamma,
                                                 const float* __restrict__ beta,
                                                 USHORT* __restrict__ NG) {
    const int row = blockIdx.x, tid = threadIdx.x;
    float s1 = 0.f, s2 = 0.f;
    const float* sp = &stats[(size_t)row * 32];
#pragma unroll
    for (int hh = 0; hh < 8; hh++) {
        float4 v = *(const float4*)(sp + hh * 4);
        s1 += v.x + v.z; s2 += v.y + v.w;
    }
    const float mu  = s1 * (1.0f / 1024.0f);
    const float var = s2 * (1.0f / 1024.0f) - mu * mu;
    const float inv = rsqrtf(fmaxf(var, 0.0f) + 1e-5f);
    ushort4 rv = *(const ushort4*)&R[(size_t)row * 1024 + tid * 4];
    ushort4 g4 = *(const ushort4*)&G[(size_t)row * 1024 + tid * 4];
    float4 gm = *(const float4*)&gamma[tid * 4];
    float4 bt = *(const float4*)&beta[tid * 4];
    float  vv[4]  = { bf2f(rv.x), bf2f(rv.y), bf2f(rv.z), bf2f(rv.w) };
    USHORT gg[4]  = { g4.x, g4.y, g4.z, g4.w };
    float  gmm[4] = { gm.x, gm.y, gm.z, gm.w };
    float  btt[4] = { bt.x, bt.y, bt.z, bt.w };
    USHORT o4[4];
#pragma unroll
    for (int u = 0; u < 4; u++) {
        float nv = (vv[u] - mu) * inv * gmm[u] + btt[u];
        o4[u] = f2bf(nv * bf2f(gg[u]));
    }
    *(ushort4*)&NG[(size_t)row * 1024 + tid * 4] = make_ushort4(o4[0], o4[1], o4[2], o4[3]);
}

// ---------------------------------------------------------------------------
extern "C" void kernel_launch(void* const* d_in, const int* in_sizes, int n_in,
                              void* d_out, int out_size, void* d_ws, size_t ws_size,
                              hipStream_t stream) {
    const float* x     = (const float*)d_in[0];
    const float* Wq    = (const float*)d_in[1];
    const float* bq    = (const float*)d_in[2];
    const float* Wk    = (const float*)d_in[3];
    const float* bk    = (const float*)d_in[4];
    const float* Wv    = (const float*)d_in[5];
    const float* bv    = (const float*)d_in[6];
    const float* Wg    = (const float*)d_in[7];
    const float* bg    = (const float*)d_in[8];
    const float* Wo    = (const float*)d_in[9];
    const float* bo    = (const float*)d_in[10];
    const float* gamma = (const float*)d_in[11];
    const float* beta  = (const float*)d_in[12];

    // ws (42.5 MB): WT x5 | Qb -> NGb | Kb -> R (in-place) | VTb | Gb | stats
    char* ws = (char*)d_ws;
    const size_t MB = 1 << 20;
    USHORT* WqT = (USHORT*)(ws + 0 * MB);
    USHORT* WkT = (USHORT*)(ws + 2 * MB);
    USHORT* WvT = (USHORT*)(ws + 4 * MB);
    USHORT* WgT = (USHORT*)(ws + 6 * MB);
    USHORT* WoT = (USHORT*)(ws + 8 * MB);
    USHORT* Qb  = (USHORT*)(ws + 10 * MB);
    USHORT* Kb  = (USHORT*)(ws + 18 * MB);   // becomes R bf16 after k_apply
    USHORT* VTb = (USHORT*)(ws + 26 * MB);
    USHORT* Gb  = (USHORT*)(ws + 34 * MB);
    float*  Sts = (float*) (ws + 42 * MB);   // [4096][16][2] per-head partials
    USHORT* NGb = Qb;                        // Qb dead after apply
    USHORT* Xb  = (USHORT*)d_out;            // bf16 x; dead after proj
    float*  Ust = (float*)d_out;             // U -> scanned S; dead after apply

    {   // 1. prep: transpose 5 weights + cast x
        PrepArgs pa;
        pa.src[0] = Wq; pa.src[1] = Wk; pa.src[2] = Wv; pa.src[3] = Wg; pa.src[4] = Wo;
        pa.dst[0] = WqT; pa.dst[1] = WkT; pa.dst[2] = WvT; pa.dst[3] = WgT; pa.dst[4] = WoT;
        pa.x = x; pa.xb = Xb;
        k_prep<<<dim3(16, 16, 6), 256, 0, stream>>>(pa);
    }
    {   // 2. fused projections: Q(.125), K, VT(+decay), G(sigmoid)
        static int s_256ok = -1;
        if (s_256ok < 0) {
            hipError_t e = hipFuncSetAttribute(
                reinterpret_cast<const void*>(&k_gemm256),
                hipFuncAttributeMaxDynamicSharedMemorySize, 131072);
            s_256ok = (e == hipSuccess) ? 1 : 0;
        }
        GArgs ga;
        ga.A = Xb;
        ga.W[0] = WqT; ga.W[1] = WkT; ga.W[2] = WvT; ga.W[3] = WgT;
        ga.bias[0] = bq; ga.bias[1] = bk; ga.bias[2] = bv; ga.bias[3] = bg;
        ga.dst[0] = Qb; ga.dst[1] = Kb; ga.dst[2] = nullptr; ga.dst[3] = Gb;
        ga.dstv = VTb;
        ga.scale[0] = 0.125f; ga.scale[1] = 1.0f; ga.scale[2] = 1.0f; ga.scale[3] = 1.0f;
        ga.mode[0] = 0; ga.mode[1] = 0; ga.mode[2] = 2; ga.mode[3] = 1;
        if (s_256ok)
            k_gemm256<<<dim3(4, 16, 4), 512, 131072, stream>>>(ga);
        else
            k_gemm<<<dim3(8, 32, 4), 256, 0, stream>>>(ga);
    }
    // 3. chunk outer products U (into d_out; Xb dead)
    k_attn_u<<<dim3(32, 32), 256, 0, stream>>>(Kb, VTb, Ust);
    // 3b. in-place decayed prefix scan: U_c -> S_c
    k_scan<<<dim3(32, 4), 256, 0, stream>>>(Ust);
    // 4. apply: S-read + diag + cross + per-head LN stats; R bf16 in-place over Kb
    k_apply<<<dim3(32, 32), 256, 0, stream>>>(Qb, Kb, VTb, Ust, Kb, Sts);
    // 5. LayerNorm + gate -> NGb (= dead Qb)
    k_ln_gate<<<4096, 256, 0, stream>>>(Kb, Gb, Sts, gamma, beta, NGb);
    // 6. output projection: 64x128 tiles -> 512 blocks (2+/CU) -> d_out fp32
    k_gemm_out<<<dim3(8, 64), 256, 0, stream>>>(NGb, WoT, bo, (float*)d_out);
}